// Round 19
// baseline (874.225 us; speedup 1.0000x reference)
//
#include <hip/hip_runtime.h>
#include <math.h>

#define BB 32
#define TT 512
#define SS 1024
#define HH 1024

typedef __attribute__((ext_vector_type(8))) short short8;
typedef __attribute__((ext_vector_type(4))) float f32x4;
typedef __attribute__((ext_vector_type(4))) unsigned short u16x4;
typedef unsigned short u16;
typedef unsigned int u32;

__device__ __forceinline__ u16 f2h(float x) {
    union { float f; unsigned int u; } a; a.f = x;
    unsigned int u = a.u;
    return (u16)((u + 0x7fffu + ((u >> 16) & 1u)) >> 16);
}
__device__ __forceinline__ float h2f(u16 h) {
    union { unsigned int u; float f; } a; a.u = ((unsigned int)h) << 16;
    return a.f;
}

__device__ __forceinline__ void gll16(const u16* g, u16* l) {
    __builtin_amdgcn_global_load_lds(
        (const __attribute__((address_space(1))) void*)g,
        (__attribute__((address_space(3))) void*)l, 16, 0, 0);
}

enum { E_F32 = 0, E_SPLIT = 1, E_TANH = 2, E_H = 3 };

struct Segs { const u16* a[4]; const u16* b[4]; };

// ===========================================================================
// Shared epilogue: LDS-transposed coalesced stores (R14). ebase >= 34KB.
// ===========================================================================
#define EPILOGUE_STORE(EPI_, ebase_, acc_, bm_, bn_, ldC_, Cf_, Ch_, Cl_,      \
                       bias_, tid_, wr_, wc_, fr_, g_)                         \
{                                                                              \
    __syncthreads();                                                           \
    const int lrow = (wr_) * 16 + (g_) * 4;                                    \
    _Pragma("unroll")                                                          \
    for (int mi = 0; mi < 8; ++mi) {                                           \
        if ((EPI_) == E_F32 || (EPI_) == E_TANH) {                             \
            float* el = (float*)(ebase_);                                      \
            _Pragma("unroll")                                                  \
            for (int nj = 0; nj < 4; ++nj) {                                   \
                const int col = (wc_) * 64 + nj * 16 + (fr_);                  \
                const float bv = ((EPI_) == E_TANH) ? bias_[(bn_) + col] : 0.0f;\
                _Pragma("unroll")                                              \
                for (int r = 0; r < 4; ++r) {                                  \
                    float vv = acc_[mi][nj][r];                                \
                    if ((EPI_) == E_TANH) {                                    \
                        const float e = __expf(2.0f * (vv + bv));              \
                        vv = 1.0f - 2.0f / (e + 1.0f);                         \
                    }                                                          \
                    el[(lrow + r) * 260 + col] = vv;                           \
                }                                                              \
            }                                                                  \
            __syncthreads();                                                   \
            _Pragma("unroll")                                                  \
            for (int q = 0; q < 4; ++q) {                                      \
                const int c = (tid_) + 512 * q;                                \
                const int r32 = c >> 6, c4 = (c & 63) * 4;                     \
                f32x4 vv = *(const f32x4*)&el[r32 * 260 + c4];                 \
                const int grow = (bm_) + (r32 >> 4) * 128 + mi * 16 + (r32 & 15);\
                *(f32x4*)&Cf_[(long)grow * (ldC_) + (bn_) + c4] = vv;          \
            }                                                                  \
        } else if ((EPI_) == E_SPLIT) {                                        \
            u32* el = (u32*)(ebase_);                                          \
            _Pragma("unroll")                                                  \
            for (int nj = 0; nj < 4; ++nj) {                                   \
                const int col = (wc_) * 64 + nj * 16 + (fr_);                  \
                _Pragma("unroll")                                              \
                for (int r = 0; r < 4; ++r) {                                  \
                    const float vv = acc_[mi][nj][r];                          \
                    const u16 h = f2h(vv);                                     \
                    const u16 lo = f2h(vv - h2f(h));                           \
                    el[(lrow + r) * 260 + col] = (u32)h | ((u32)lo << 16);     \
                }                                                              \
            }                                                                  \
            __syncthreads();                                                   \
            _Pragma("unroll")                                                  \
            for (int q = 0; q < 4; ++q) {                                      \
                const int c = (tid_) + 512 * q;                                \
                const int r32 = c >> 6, c4 = (c & 63) * 4;                     \
                const u32* p = &el[r32 * 260 + c4];                            \
                u16x4 hh, ll;                                                  \
                _Pragma("unroll")                                              \
                for (int e = 0; e < 4; ++e) {                                  \
                    const u32 pv = p[e];                                       \
                    hh[e] = (u16)(pv & 0xffffu);                               \
                    ll[e] = (u16)(pv >> 16);                                   \
                }                                                              \
                const int grow = (bm_) + (r32 >> 4) * 128 + mi * 16 + (r32 & 15);\
                const long o = (long)grow * (ldC_) + (bn_) + c4;               \
                *(u16x4*)&Ch_[o] = hh;                                         \
                *(u16x4*)&Cl_[o] = ll;                                         \
            }                                                                  \
        } else {                                                               \
            u16* el = (u16*)(ebase_);                                          \
            _Pragma("unroll")                                                  \
            for (int nj = 0; nj < 4; ++nj) {                                   \
                const int col = (wc_) * 64 + nj * 16 + (fr_);                  \
                _Pragma("unroll")                                              \
                for (int r = 0; r < 4; ++r)                                    \
                    el[(lrow + r) * 264 + col] = f2h(acc_[mi][nj][r]);         \
            }                                                                  \
            __syncthreads();                                                   \
            _Pragma("unroll")                                                  \
            for (int q = 0; q < 2; ++q) {                                      \
                const int c = (tid_) + 512 * q;                                \
                const int r32 = c >> 5, c8 = (c & 31) * 8;                     \
                short8 vv = *(const short8*)&el[r32 * 264 + c8];               \
                const int grow = (bm_) + (r32 >> 4) * 128 + mi * 16 + (r32 & 15);\
                *(short8*)&Ch_[(long)grow * (ldC_) + (bn_) + c8] = vv;         \
            }                                                                  \
        }                                                                      \
        __syncthreads();                                                       \
    }                                                                          \
}

// ===========================================================================
// gemm_f3 — 3-product (Ah·Bh + Ah·Bl + Al·Bh), K=1024, 256x256 tile,
// 3 phases/tile x 32-MFMA clusters. launch_bounds(512,1): ~244 live VGPRs
// (acc 128 + frags 96 + addr) — (512,2)'s 128-cap caused the R18 spill
// catastrophe (FETCH 798MB, WRITE 1.2GB scratch traffic, MfmaUtil 10%).
// Grid is 256 = 1 block/CU anyway, so no occupancy is lost.
// ===========================================================================
template<int EPI>
__global__ __launch_bounds__(512, 1) void gemm_f3(
    const u16* __restrict__ Ah_g, const u16* __restrict__ Al_g,
    const u16* __restrict__ Bh_g, const u16* __restrict__ Bl_g,
    int ldA, int ldB, int zshift,
    long sA, long sB, long sC,
    const float* __restrict__ bias,
    float* __restrict__ Cf, u16* __restrict__ Ch, u16* __restrict__ Cl,
    int ldC)
{
    __shared__ u16 lds[2][4][256 * 32];   // 0=Ah 1=Bh 2=Bl 3=Al ; 128 KiB

    const int tid = threadIdx.x;
    const int l = tid & 63, w = tid >> 6;
    const int wr = w >> 2, wc = w & 3;
    const int fr = l & 15, g = l >> 4;

    const int id = blockIdx.x;
    const int v = ((id & 7) << 5) | (id >> 3);
    const int z = v >> zshift;
    const int rest = v & ((1 << zshift) - 1);
    const int bm = (rest >> 2) * 256;
    const int bn = (rest & 3) * 256;

    const u16* Ah = Ah_g + (long)z * sA;
    const u16* Al = Al_g + (long)z * sA;
    const u16* Bh = Bh_g + (long)z * sB;
    const u16* Bl = Bl_g + (long)z * sB;
    if (EPI == E_F32 || EPI == E_TANH) Cf += (long)z * sC;
    else { Ch += (long)z * sC; if (EPI == E_SPLIT) Cl += (long)z * sC; }

    f32x4 acc[8][4] = {};

    const int srow = tid >> 2, sch = tid & 3;
    const int skc = sch ^ ((srow >> 1) & 3);
    const long grA0 = (long)(bm + srow) * ldA + skc * 8;
    const long grA1 = (long)(bm + 128 + srow) * ldA + skc * 8;
    const long grB0 = (long)(bn + srow) * ldB + skc * 8;
    const long grB1 = (long)(bn + 128 + srow) * ldB + skc * 8;
    const int ldst0 = (tid & ~63) * 8;
    const int ldst1 = (512 + (tid & ~63)) * 8;

    auto stage = [&](int tile, int ten) {
        const int k0g = tile * 32;
        u16* lb = &lds[tile & 1][ten][0];
        const u16* base = (ten == 0) ? Ah : (ten == 1) ? Bh : (ten == 2) ? Bl : Al;
        if (ten == 0 || ten == 3) {
            gll16(base + grA0 + k0g, lb + ldst0);
            gll16(base + grA1 + k0g, lb + ldst1);
        } else {
            gll16(base + grB0 + k0g, lb + ldst0);
            gll16(base + grB1 + k0g, lb + ldst1);
        }
    };

    int offA[8], offB[4];
#pragma unroll
    for (int k = 0; k < 8; ++k) {
        const int r = wr * 128 + k * 16 + fr;
        offA[k] = (r * 4 + (g ^ ((r >> 1) & 3))) * 8;
    }
#pragma unroll
    for (int j = 0; j < 4; ++j) {
        const int r = wc * 64 + j * 16 + fr;
        offB[j] = (r * 4 + (g ^ ((r >> 1) & 3))) * 8;
    }

    short8 AH[8], AL8[8], BH[4], BL[4];

#define PFA8(DST, BUF, TEN)                                                    \
    { const u16* pl = &lds[BUF][TEN][0];                                       \
      _Pragma("unroll") for (int i_ = 0; i_ < 8; ++i_)                         \
          DST[i_] = *(const short8*)&pl[offA[i_]]; }
#define PFB4(DST, BUF, TEN)                                                    \
    { const u16* pl = &lds[BUF][TEN][0];                                       \
      _Pragma("unroll") for (int j_ = 0; j_ < 4; ++j_)                         \
          DST[j_] = *(const short8*)&pl[offB[j_]]; }
#define MFMA32(FA, FB)                                                         \
    __builtin_amdgcn_s_setprio(1);                                             \
    _Pragma("unroll") for (int i_ = 0; i_ < 8; ++i_)                           \
        _Pragma("unroll") for (int j_ = 0; j_ < 4; ++j_)                       \
            acc[i_][j_] = __builtin_amdgcn_mfma_f32_16x16x32_bf16(             \
                FA[i_], FB[j_], acc[i_][j_], 0, 0, 0);                         \
    __builtin_amdgcn_s_setprio(0);

    // prologue: stage tile0 (Ah,Bh,Bl,Al = 8 gll); retire all but Al; PF P1 ops
    stage(0, 0); stage(0, 1); stage(0, 2); stage(0, 3);
    asm volatile("s_waitcnt vmcnt(2)" ::: "memory");
    __builtin_amdgcn_s_barrier();
    PFA8(AH, 0, 0)
    PFB4(BL, 0, 2)
    __builtin_amdgcn_sched_barrier(0);

    const int NT = 32;   // K = 1024
    for (int t = 0; t < NT; ++t) {
        const int cur = t & 1, nxt = cur ^ 1;
        const bool nl = (t + 1 < NT);

        // P1: MFMA AhBl; stage Ah,Bl(t+1); PF BH(cur)
        if (nl) { stage(t + 1, 0); stage(t + 1, 2); }
        if (nl) { asm volatile("s_waitcnt vmcnt(6)" ::: "memory"); }
        else    { asm volatile("s_waitcnt vmcnt(2)" ::: "memory"); }
        __builtin_amdgcn_s_barrier();
        PFB4(BH, cur, 1)
        __builtin_amdgcn_sched_barrier(0);
        MFMA32(AH, BL)

        // P2: MFMA AhBh; stage Bh,Al(t+1); PF AL(cur)
        if (nl) { stage(t + 1, 1); stage(t + 1, 3); }
        if (nl) { asm volatile("s_waitcnt vmcnt(8)" ::: "memory"); }
        else    { asm volatile("s_waitcnt vmcnt(0)" ::: "memory"); }
        __builtin_amdgcn_s_barrier();
        PFA8(AL8, cur, 3)
        __builtin_amdgcn_sched_barrier(0);
        MFMA32(AH, BH)

        // P3: MFMA AlBh; PF AH(nxt),BL(nxt)
        if (nl) { asm volatile("s_waitcnt vmcnt(4)" ::: "memory"); }
        __builtin_amdgcn_s_barrier();
        if (nl) { PFA8(AH, nxt, 0) PFB4(BL, nxt, 2) }
        __builtin_amdgcn_sched_barrier(0);
        MFMA32(AL8, BH)
    }
#undef PFA8
#undef PFB4
#undef MFMA32

    u16* ebase = (u16*)&lds[0][0][0];
    EPILOGUE_STORE(EPI, ebase, acc, bm, bn, ldC, Cf, Ch, Cl, bias,
                   tid, wr, wc, fr, g)
}

// ===========================================================================
// gemm_f2 — 2-product (Ah·(Bh+Bl)), K=2048 via A = [Ah0|Ah1] k-concat,
// 2 phases/tile x 32 MFMA; AH ping-pong (AHa/AHb), x2 unrolled (rule 20).
// launch_bounds(512,1) for the same spill reason as gemm_f3.
// ===========================================================================
template<int EPI>
__global__ __launch_bounds__(512, 1) void gemm_f2(
    const u16* __restrict__ Ah0_g, const u16* __restrict__ Ah1_g,
    const u16* __restrict__ Bh_g, const u16* __restrict__ Bl_g,
    int ldA, int ldB, int zshift,
    long sA, long sB, long sC,
    const float* __restrict__ bias,
    float* __restrict__ Cf, u16* __restrict__ Ch, u16* __restrict__ Cl,
    int ldC)
{
    __shared__ u16 lds[2][3][256 * 32];   // 0=Ah 1=Bh 2=Bl ; 96 KiB

    const int tid = threadIdx.x;
    const int l = tid & 63, w = tid >> 6;
    const int wr = w >> 2, wc = w & 3;
    const int fr = l & 15, g = l >> 4;

    const int id = blockIdx.x;
    const int v = ((id & 7) << 5) | (id >> 3);
    const int z = v >> zshift;
    const int rest = v & ((1 << zshift) - 1);
    const int bm = (rest >> 2) * 256;
    const int bn = (rest & 3) * 256;

    const u16* Ah0 = Ah0_g + (long)z * sA;
    const u16* Ah1 = Ah1_g;
    const u16* Bh  = Bh_g + (long)z * sB;
    const u16* Bl  = Bl_g + (long)z * sB;
    if (EPI == E_F32 || EPI == E_TANH) Cf += (long)z * sC;
    else { Ch += (long)z * sC; if (EPI == E_SPLIT) Cl += (long)z * sC; }

    f32x4 acc[8][4] = {};

    const int srow = tid >> 2, sch = tid & 3;
    const int skc = sch ^ ((srow >> 1) & 3);
    const long grA0 = (long)(bm + srow) * ldA + skc * 8;
    const long grA1 = (long)(bm + 128 + srow) * ldA + skc * 8;
    const long grB0 = (long)(bn + srow) * ldB + skc * 8;
    const long grB1 = (long)(bn + 128 + srow) * ldB + skc * 8;
    const int ldst0 = (tid & ~63) * 8;
    const int ldst1 = (512 + (tid & ~63)) * 8;

    auto stage = [&](int tile, int ten) {
        const int k0g = tile * 32;
        u16* lb = &lds[tile & 1][ten][0];
        if (ten == 0) {
            const u16* base = (k0g >= 1024) ? Ah1 : Ah0;
            const int ka = k0g & 1023;
            gll16(base + grA0 + ka, lb + ldst0);
            gll16(base + grA1 + ka, lb + ldst1);
        } else {
            const u16* b = (ten == 1) ? Bh : Bl;
            gll16(b + grB0 + k0g, lb + ldst0);
            gll16(b + grB1 + k0g, lb + ldst1);
        }
    };

    int offA[8], offB[4];
#pragma unroll
    for (int k = 0; k < 8; ++k) {
        const int r = wr * 128 + k * 16 + fr;
        offA[k] = (r * 4 + (g ^ ((r >> 1) & 3))) * 8;
    }
#pragma unroll
    for (int j = 0; j < 4; ++j) {
        const int r = wc * 64 + j * 16 + fr;
        offB[j] = (r * 4 + (g ^ ((r >> 1) & 3))) * 8;
    }

    short8 AHa[8], AHb[8], BH[4], BL[4];

#define PFA8(DST, BUF, TEN)                                                    \
    { const u16* pl = &lds[BUF][TEN][0];                                       \
      _Pragma("unroll") for (int i_ = 0; i_ < 8; ++i_)                         \
          DST[i_] = *(const short8*)&pl[offA[i_]]; }
#define PFB4(DST, BUF, TEN)                                                    \
    { const u16* pl = &lds[BUF][TEN][0];                                       \
      _Pragma("unroll") for (int j_ = 0; j_ < 4; ++j_)                         \
          DST[j_] = *(const short8*)&pl[offB[j_]]; }
#define MFMA32(FA, FB)                                                         \
    __builtin_amdgcn_s_setprio(1);                                             \
    _Pragma("unroll") for (int i_ = 0; i_ < 8; ++i_)                           \
        _Pragma("unroll") for (int j_ = 0; j_ < 4; ++j_)                       \
            acc[i_][j_] = __builtin_amdgcn_mfma_f32_16x16x32_bf16(             \
                FA[i_], FB[j_], acc[i_][j_], 0, 0, 0);                         \
    __builtin_amdgcn_s_setprio(0);

#define TILE_BODY(T, AHC, AHN)                                                 \
    {                                                                          \
        const int cur_ = (T) & 1, nxt_ = cur_ ^ 1;                             \
        const bool nl_ = ((T) + 1 < NT);                                       \
        /* P1: stage Ah,Bh(t+1); wait retires prev Bl; PF BL(cur) */           \
        if (nl_) { stage((T) + 1, 0); stage((T) + 1, 1); }                     \
        if (nl_) { asm volatile("s_waitcnt vmcnt(4)" ::: "memory"); }          \
        else     { asm volatile("s_waitcnt vmcnt(0)" ::: "memory"); }          \
        __builtin_amdgcn_s_barrier();                                          \
        PFB4(BL, cur_, 2)                                                      \
        __builtin_amdgcn_sched_barrier(0);                                     \
        MFMA32(AHC, BH)                                                        \
        /* P2: stage Bl(t+1); wait retires Ah,Bh(t+1); PF AHN,BH(nxt) */       \
        if (nl_) { stage((T) + 1, 2); }                                        \
        if (nl_) { asm volatile("s_waitcnt vmcnt(2)" ::: "memory"); }          \
        __builtin_amdgcn_s_barrier();                                          \
        if (nl_) { PFA8(AHN, nxt_, 0) PFB4(BH, nxt_, 1) }                      \
        __builtin_amdgcn_sched_barrier(0);                                     \
        MFMA32(AHC, BL)                                                        \
    }

    // prologue
    stage(0, 0); stage(0, 1); stage(0, 2);
    asm volatile("s_waitcnt vmcnt(2)" ::: "memory");
    __builtin_amdgcn_s_barrier();
    PFA8(AHa, 0, 0)
    PFB4(BH, 0, 1)
    __builtin_amdgcn_sched_barrier(0);

    const int NT = 64;   // K = 2048
    for (int t2 = 0; t2 < NT; t2 += 2) {
        TILE_BODY(t2, AHa, AHb)
        TILE_BODY(t2 + 1, AHb, AHa)
    }
#undef TILE_BODY
#undef PFA8
#undef PFB4
#undef MFMA32

    u16* ebase = (u16*)&lds[0][0][0];
    EPILOGUE_STORE(EPI, ebase, acc, bm, bn, ldC, Cf, Ch, Cl, bias,
                   tid, wr, wc, fr, g)
}

// ===========================================================================
// R9-family gemm8 (K'-extension) — retained for K3 (NSEG=1, native).
// ===========================================================================
template<int NSEG, int EPI>
__global__ __launch_bounds__(512, 2) void gemm8(
    Segs sg, int ldA, int ldB, int zshift,
    long sA, long sB, long sC,
    const float* __restrict__ bias,
    float* __restrict__ Cf, u16* __restrict__ Ch, u16* __restrict__ Cl,
    int ldC)
{
    __shared__ u16 lds[2][2][2][256 * 32];

    const int tid = threadIdx.x;
    const int l = tid & 63, w = tid >> 6;
    const int wr = w >> 2, wc = w & 3;
    const int fr = l & 15, g = l >> 4;

    const int id = blockIdx.x;
    const int v = ((id & 7) << 5) | (id >> 3);
    const int z = v >> zshift;
    const int rest = v & ((1 << zshift) - 1);
    const int bm = (rest >> 2) * 256;
    const int bn = (rest & 3) * 256;

    const u16* Aseg[4]; const u16* Bseg[4];
#pragma unroll
    for (int s = 0; s < NSEG; ++s) {
        Aseg[s] = sg.a[s] + (long)z * sA;
        Bseg[s] = sg.b[s] + (long)z * sB;
    }
    if (EPI == E_F32 || EPI == E_TANH) Cf += (long)z * sC;
    else { Ch += (long)z * sC; if (EPI == E_SPLIT) Cl += (long)z * sC; }

    f32x4 acc[8][4] = {};

    const int srow = tid >> 2, sch = tid & 3;
    const int skc = sch ^ ((srow >> 1) & 3);
    const long grA0 = (long)(bm + srow) * ldA + skc * 8;
    const long grA1 = (long)(bm + 128 + srow) * ldA + skc * 8;
    const long grB0 = (long)(bn + srow) * ldB + skc * 8;
    const long grB1 = (long)(bn + 128 + srow) * ldB + skc * 8;
    const int ldst0 = (tid & ~63) * 8;
    const int ldst1 = (512 + (tid & ~63)) * 8;

    auto stage = [&](int tile, int kh, int tensor) {
        const int k0g = tile * 64 + kh * 32;
        const int seg = k0g >> 10, kl = k0g & 1023;
        u16* lb = &lds[tile & 1][tensor][kh][0];
        if (tensor) {
            const u16* b = Bseg[seg];
            gll16(b + grB0 + kl, lb + ldst0);
            gll16(b + grB1 + kl, lb + ldst1);
        } else {
            const u16* a = Aseg[seg];
            gll16(a + grA0 + kl, lb + ldst0);
            gll16(a + grA1 + kl, lb + ldst1);
        }
    };

    int offA[8], offB[4];
#pragma unroll
    for (int k = 0; k < 8; ++k) {
        const int r = wr * 128 + k * 16 + fr;
        offA[k] = (r * 4 + (g ^ ((r >> 1) & 3))) * 8;
    }
#pragma unroll
    for (int j = 0; j < 4; ++j) {
        const int r = wc * 64 + j * 16 + fr;
        offB[j] = (r * 4 + (g ^ ((r >> 1) & 3))) * 8;
    }

    short8 faX[4], faY[4], fbA[4], fbB[4];

#define PFA(FA, BUF, KS, MH)                                                   \
    { const u16* pl = &lds[BUF][0][KS][0];                                     \
      _Pragma("unroll") for (int i_ = 0; i_ < 4; ++i_)                         \
          FA[i_] = *(const short8*)&pl[offA[(MH) * 4 + i_]]; }
#define PFB(FB, BUF, KS)                                                       \
    { const u16* pl = &lds[BUF][1][KS][0];                                     \
      _Pragma("unroll") for (int j_ = 0; j_ < 4; ++j_)                         \
          FB[j_] = *(const short8*)&pl[offB[j_]]; }
#define MFMA16(FA, FB, MH)                                                     \
    __builtin_amdgcn_s_setprio(1);                                             \
    _Pragma("unroll") for (int i_ = 0; i_ < 4; ++i_)                           \
        _Pragma("unroll") for (int j_ = 0; j_ < 4; ++j_)                       \
            acc[(MH) * 4 + i_][j_] = __builtin_amdgcn_mfma_f32_16x16x32_bf16(  \
                FA[i_], FB[j_], acc[(MH) * 4 + i_][j_], 0, 0, 0);              \
    __builtin_amdgcn_s_setprio(0);

    stage(0, 0, 0); stage(0, 0, 1); stage(0, 1, 0); stage(0, 1, 1);
    asm volatile("s_waitcnt vmcnt(0)" ::: "memory");
    __builtin_amdgcn_s_barrier();
    PFB(fbA, 0, 0)
    PFA(faX, 0, 0, 0)
    __builtin_amdgcn_sched_barrier(0);

    const int NT = NSEG * 16;
    for (int t = 0; t < NT; ++t) {
        const int cur = t & 1, nxt = cur ^ 1;
        const bool nl = (t + 1 < NT);

        if (nl) stage(t + 1, 0, 0);
        __builtin_amdgcn_s_barrier();
        PFA(faY, cur, 0, 1)
        __builtin_amdgcn_sched_barrier(0);
        MFMA16(faX, fbA, 0)

        if (nl) stage(t + 1, 0, 1);
        if (nl) { asm volatile("s_waitcnt vmcnt(4)" ::: "memory"); }
        else    { asm volatile("s_waitcnt vmcnt(0)" ::: "memory"); }
        __builtin_amdgcn_s_barrier();
        PFB(fbB, cur, 1)
        PFA(faX, cur, 1, 0)
        __builtin_amdgcn_sched_barrier(0);
        MFMA16(faY, fbA, 1)

        if (nl) stage(t + 1, 1, 0);
        __builtin_amdgcn_s_barrier();
        PFA(faY, cur, 1, 1)
        __builtin_amdgcn_sched_barrier(0);
        MFMA16(faX, fbB, 0)

        if (nl) stage(t + 1, 1, 1);
        if (nl) { asm volatile("s_waitcnt vmcnt(4)" ::: "memory"); }
        __builtin_amdgcn_s_barrier();
        PFB(fbA, nxt, 0)
        PFA(faX, nxt, 0, 0)
        __builtin_amdgcn_sched_barrier(0);
        MFMA16(faY, fbB, 1)
    }
#undef PFA
#undef PFB
#undef MFMA16

    u16* ebase = (u16*)&lds[0][0][0][0];
    EPILOGUE_STORE(EPI, ebase, acc, bm, bn, ldC, Cf, Ch, Cl, bias,
                   tid, wr, wc, fr, g)
}

// ---------------------------------------------------------------------------
__global__ __launch_bounds__(256) void split_f32(
    const float* __restrict__ in, u16* __restrict__ hi, u16* __restrict__ lo,
    long n4)
{
    long i = (long)blockIdx.x * blockDim.x + threadIdx.x;
    const long stride = (long)gridDim.x * blockDim.x;
    for (; i < n4; i += stride) {
        f32x4 v = *(const f32x4*)(in + i * 4);
        u16x4 h4, l4;
#pragma unroll
        for (int e = 0; e < 4; ++e) {
            u16 h_ = f2h(v[e]);
            h4[e] = h_; l4[e] = f2h(v[e] - h2f(h_));
        }
        *(u16x4*)(hi + i * 4) = h4;
        *(u16x4*)(lo + i * 4) = l4;
    }
}

__global__ __launch_bounds__(256) void split3(
    const float* __restrict__ q,  u16* __restrict__ qh,  u16* __restrict__ ql,
    const float* __restrict__ wi, u16* __restrict__ wih, u16* __restrict__ wil,
    const float* __restrict__ wo, u16* __restrict__ woh, u16* __restrict__ wol,
    long nq4, long nwi4, long nwo4)
{
    const long total = nq4 + nwi4 + nwo4;
    long i = (long)blockIdx.x * blockDim.x + threadIdx.x;
    const long stride = (long)gridDim.x * blockDim.x;
    for (; i < total; i += stride) {
        const float* src; u16 *hi, *lo; long off;
        if (i < nq4)              { src = q;  hi = qh;  lo = ql;  off = i; }
        else if (i < nq4 + nwi4)  { src = wi; hi = wih; lo = wil; off = i - nq4; }
        else                      { src = wo; hi = woh; lo = wol; off = i - nq4 - nwi4; }
        f32x4 v = *(const f32x4*)(src + off * 4);
        u16x4 h4, l4;
#pragma unroll
        for (int e = 0; e < 4; ++e) {
            u16 h_ = f2h(v[e]);
            h4[e] = h_; l4[e] = f2h(v[e] - h2f(h_));
        }
        *(u16x4*)(hi + off * 4) = h4;
        *(u16x4*)(lo + off * 4) = l4;
    }
}

__global__ __launch_bounds__(256) void split_enc_fused(
    const float* __restrict__ in, u16* __restrict__ hi, u16* __restrict__ lo,
    u16* __restrict__ outT)
{
    __shared__ u16 t[64][72];
    const int z = blockIdx.z, sb = blockIdx.x * 64, hb = blockIdx.y * 64;
    const int c4 = (threadIdx.x & 15) * 4, r0 = threadIdx.x >> 4;
    const float* src = in + ((long)z * SS + sb) * HH + hb;
    u16* dhi = hi + ((long)z * SS + sb) * HH + hb;
    u16* dlo = lo + ((long)z * SS + sb) * HH + hb;
#pragma unroll
    for (int i = 0; i < 4; ++i) {
        const int r = r0 + i * 16;
        f32x4 v = *(const f32x4*)(src + (long)r * HH + c4);
        u16x4 h4, l4;
#pragma unroll
        for (int j = 0; j < 4; ++j) {
            u16 h_ = f2h(v[j]);
            h4[j] = h_; l4[j] = f2h(v[j] - h2f(h_));
        }
        *(u16x4*)(dhi + (long)r * HH + c4) = h4;
        *(u16x4*)(dlo + (long)r * HH + c4) = l4;
        t[c4 + 0][r] = h4[0]; t[c4 + 1][r] = h4[1];
        t[c4 + 2][r] = h4[2]; t[c4 + 3][r] = h4[3];
    }
    __syncthreads();
    u16* dst = outT + ((long)z * HH + hb) * SS + sb;
#pragma unroll
    for (int i = 0; i < 4; ++i) {
        const int r = r0 + i * 16;
        u16x4 o;
#pragma unroll
        for (int j = 0; j < 4; ++j) o[j] = t[r][c4 + j];
        *(u16x4*)(dst + (long)r * SS + c4) = o;
    }
}

__global__ __launch_bounds__(256) void transpose_h(
    const u16* __restrict__ in, u16* __restrict__ out)
{
    __shared__ u16 t[64][72];
    const int z = blockIdx.z, sb = blockIdx.x * 64, hb = blockIdx.y * 64;
    const int c4 = (threadIdx.x & 15) * 4, r0 = threadIdx.x >> 4;
    const u16* src = in + ((long)z * SS + sb) * HH + hb;
#pragma unroll
    for (int i = 0; i < 4; ++i) {
        const int r = r0 + i * 16;
        u16x4 v = *(const u16x4*)(src + (long)r * HH + c4);
        t[c4 + 0][r] = v[0]; t[c4 + 1][r] = v[1];
        t[c4 + 2][r] = v[2]; t[c4 + 3][r] = v[3];
    }
    __syncthreads();
    u16* dst = out + ((long)z * HH + hb) * SS + sb;
#pragma unroll
    for (int i = 0; i < 4; ++i) {
        const int r = r0 + i * 16;
        u16x4 o;
#pragma unroll
        for (int j = 0; j < 4; ++j) o[j] = t[r][c4 + j];
        *(u16x4*)(dst + (long)r * SS + c4) = o;
    }
}

__global__ __launch_bounds__(256) void softmax_mask(
    const float* __restrict__ Sc, u16* __restrict__ Ph,
    const int* __restrict__ lens)
{
    const int row = blockIdx.x;
    const int b = row >> 9;
    const int len = lens[b];
    const float* p = Sc + (long)row * SS;

    const int tid = threadIdx.x;
    const int s0 = tid * 4;
    f32x4 v = *(const f32x4*)(p + s0);
    float vals[4] = {v.x, v.y, v.z, v.w};

    float mx = -INFINITY;
#pragma unroll
    for (int j = 0; j < 4; ++j) {
        if (s0 + j >= len) vals[j] = -INFINITY;
        mx = fmaxf(mx, vals[j]);
    }
    for (int off = 32; off; off >>= 1) mx = fmaxf(mx, __shfl_xor(mx, off, 64));

    __shared__ float redm[4];
    __shared__ float reds[4];
    const int wave = tid >> 6, lane = tid & 63;
    if (lane == 0) redm[wave] = mx;
    __syncthreads();
    mx = fmaxf(fmaxf(redm[0], redm[1]), fmaxf(redm[2], redm[3]));

    float sum = 0.0f;
#pragma unroll
    for (int j = 0; j < 4; ++j) {
        vals[j] = __expf(vals[j] - mx);
        sum += vals[j];
    }
    for (int off = 32; off; off >>= 1) sum += __shfl_xor(sum, off, 64);
    if (lane == 0) reds[wave] = sum;
    __syncthreads();
    sum = reds[0] + reds[1] + reds[2] + reds[3];

    const float inv = 1.0f / sum;
    u16x4 o;
#pragma unroll
    for (int j = 0; j < 4; ++j) o[j] = f2h(vals[j] * inv);
    *(u16x4*)(Ph + (long)row * SS + s0) = o;
}

// ---------------------------------------------------------------------------
extern "C" void kernel_launch(void* const* d_in, const int* in_sizes, int n_in,
                              void* d_out, int out_size, void* d_ws, size_t ws_size,
                              hipStream_t stream)
{
    const float* query = (const float*)d_in[0];
    const float* enc   = (const float*)d_in[1];
    const int*   lens  = (const int*)d_in[2];
    const float* W_in  = (const float*)d_in[3];
    const float* W_out = (const float*)d_in[4];
    const float* b_out = (const float*)d_in[5];
    float* out = (float*)d_out;

    const long MQ = (long)BB * TT;

    u16* qh   = (u16*)d_ws;
    u16* ql   = qh   + MQ * HH;
    u16* qwh  = ql   + MQ * HH;
    u16* qwl  = qwh  + MQ * HH;
    u16* ench = qwl  + MQ * HH;
    u16* encl = ench + (long)BB * SS * HH;
    u16* ph   = encl + (long)BB * SS * HH;
    u16* wih  = ph   + MQ * SS;
    u16* wil  = wih  + (long)HH * HH;
    u16* woh  = wil  + (long)HH * HH;
    u16* wol  = woh  + (long)HH * 2 * HH;
    float* scores = (float*)(wol + (long)HH * 2 * HH);
    u16* ch   = ql;                               // overlays ql (dead after K1)

    u16* encT_ded = (u16*)(scores + MQ * SS);
    const size_t need_fused =
        (size_t)((u16*)(scores + MQ * SS) - (u16*)d_ws) * 2 + (size_t)BB * HH * SS * 2;
    const bool fused = (ws_size >= need_fused);
    u16* encTh = fused ? encT_ded : (u16*)scores;

    split3<<<2048, 256, 0, stream>>>(
        query, qh, ql, W_in, wih, wil, W_out, woh, wol,
        MQ * HH / 4, (long)HH * HH / 4, (long)HH * 2 * HH / 4);
    if (fused) {
        split_enc_fused<<<dim3(16, 16, 32), 256, 0, stream>>>(
            enc, ench, encl, encTh);
    } else {
        split_f32<<<2048, 256, 0, stream>>>(enc, ench, encl,
                                            (long)BB * SS * HH / 4);
    }

    // K1: qw = query @ W_in^T  (3-product, 3-phase/tile)
    gemm_f3<E_SPLIT><<<256, 512, 0, stream>>>(
        qh, ql, wih, wil, HH, HH, 8, 0L, 0L, 0L,
        nullptr, nullptr, qwh, qwl, HH);

    // K2: scores[b] = qw[b] @ enc[b]^T  (3-product, 3-phase/tile), 32 batches
    gemm_f3<E_F32><<<256, 512, 0, stream>>>(
        qwh, qwl, ench, encl, HH, HH, 3,
        (long)TT * HH, (long)SS * HH, (long)TT * SS,
        nullptr, scores, nullptr, nullptr, SS);

    softmax_mask<<<BB * TT, 256, 0, stream>>>(scores, ph, lens);

    if (!fused) {
        transpose_h<<<dim3(16, 16, 32), 256, 0, stream>>>(ench, encTh);
    }

    // K3: c[b] = P[b] @ enc[b]  (1-product, gemm8 NSEG=1)
    Segs s3 = {{ph, nullptr, nullptr, nullptr}, {encTh, nullptr, nullptr, nullptr}};
    gemm8<1, E_H><<<256, 512, 0, stream>>>(
        s3, SS, SS, 3, (long)TT * SS, (long)HH * SS, (long)TT * HH,
        nullptr, nullptr, ch, nullptr, HH);

    // K4: out = tanh([qh|ch] @ (Wh+Wl)^T + b)  (2-product, 2-phase/tile)
    gemm_f2<E_TANH><<<256, 512, 0, stream>>>(
        qh, ch, woh, wol, HH, 2 * HH, 8, 0L, 0L, 0L,
        b_out, out, nullptr, nullptr, HH);
}

// Round 20
// 444.770 us; speedup vs baseline: 1.9656x; 1.9656x over previous
//
#include <hip/hip_runtime.h>
#include <math.h>

#define BB 32
#define TT 512
#define SS 1024
#define HH 1024

typedef __attribute__((ext_vector_type(8))) short short8;
typedef __attribute__((ext_vector_type(4))) float f32x4;
typedef __attribute__((ext_vector_type(4))) unsigned short u16x4;
typedef unsigned short u16;
typedef unsigned int u32;

__device__ __forceinline__ u16 f2h(float x) {
    union { float f; unsigned int u; } a; a.f = x;
    unsigned int u = a.u;
    return (u16)((u + 0x7fffu + ((u >> 16) & 1u)) >> 16);
}
__device__ __forceinline__ float h2f(u16 h) {
    union { unsigned int u; float f; } a; a.u = ((unsigned int)h) << 16;
    return a.f;
}

__device__ __forceinline__ void gll16(const u16* g, u16* l) {
    __builtin_amdgcn_global_load_lds(
        (const __attribute__((address_space(1))) void*)g,
        (__attribute__((address_space(3))) void*)l, 16, 0, 0);
}

enum { E_F32 = 0, E_SPLIT = 1, E_TANH = 2, E_H = 3 };

struct Segs { const u16* a[4]; const u16* b[4]; };

// ---------------------------------------------------------------------------
// Native N-product split GEMM (R16, best measured: 445 µs total):
// C = Ah·Bh^T [+ Ah·Bl^T + Al·Bh^T]. Each real K-tile staged ONCE per tensor
// then reused across products (-33% gll16/LDS/ds_read vs K'-extension).
// 512 thr = 8 waves (2Mx4N), 16-MFMA phases (fits 236 <= 256 VGPR+AGPR cap
// that 512-thread blocks force: 2 waves/SIMD x 512-reg pool — the 32-MFMA
// variant spills structurally, R17-R19). Phase order (NPROD=3): AhBh0,
// AhBl0, AlBh0, AhBh1, AlBh1 (fbh last use), AhBl1 (+PF next — targets dead).
// vmcnt: prologue 4; ph1 retires Bl(t); ph2 retires Al(t); ph6 retires
// Ah,Bh(t+1); max 8 outstanding, never drained mid-loop.
// ---------------------------------------------------------------------------
template<int NPROD, int NKSEG, int EPI>
__global__ __launch_bounds__(512, 2) void gemm_np(
    const u16* __restrict__ Ah0_g, const u16* __restrict__ Ah1_g,
    const u16* __restrict__ Al_g,
    const u16* __restrict__ Bh_g, const u16* __restrict__ Bl_g,
    int ldA, int ldB, int zshift,
    long sA, long sB, long sC,
    const float* __restrict__ bias,
    float* __restrict__ Cf, u16* __restrict__ Ch, u16* __restrict__ Cl,
    int ldC)
{
    constexpr int NTEN = (NPROD == 3) ? 4 : 3;   // 0=Ah 1=Bh 2=Bl [3=Al]
    __shared__ u16 lds[2][NTEN][256 * 32];

    const int tid = threadIdx.x;
    const int l = tid & 63, w = tid >> 6;
    const int wr = w >> 2, wc = w & 3;
    const int fr = l & 15, g = l >> 4;

    const int id = blockIdx.x;
    const int v = ((id & 7) << 5) | (id >> 3);
    const int z = v >> zshift;
    const int rest = v & ((1 << zshift) - 1);
    const int bm = (rest >> 2) * 256;
    const int bn = (rest & 3) * 256;

    const u16* Ah0 = Ah0_g + (long)z * sA;
    const u16* Ah1 = Ah1_g;
    const u16* Al  = (NPROD == 3) ? (Al_g + (long)z * sA) : nullptr;
    const u16* Bh  = Bh_g + (long)z * sB;
    const u16* Bl  = Bl_g + (long)z * sB;
    if (EPI == E_F32 || EPI == E_TANH) Cf += (long)z * sC;
    else { Ch += (long)z * sC; if (EPI == E_SPLIT) Cl += (long)z * sC; }

    f32x4 acc[8][4] = {};

    const int srow = tid >> 2, sch = tid & 3;
    const int skc = sch ^ ((srow >> 1) & 3);
    const long grA0 = (long)(bm + srow) * ldA + skc * 8;
    const long grA1 = (long)(bm + 128 + srow) * ldA + skc * 8;
    const long grB0 = (long)(bn + srow) * ldB + skc * 8;
    const long grB1 = (long)(bn + 128 + srow) * ldB + skc * 8;
    const int ldst0 = (tid & ~63) * 8;
    const int ldst1 = (512 + (tid & ~63)) * 8;

    auto stage = [&](int tile, int ten) {
        const int k0g = tile * 32;
        u16* lb = &lds[tile & 1][ten][0];
        if (ten == 0) {
            const u16* base = (NKSEG == 2 && k0g >= 1024) ? Ah1 : Ah0;
            const int ka = (NKSEG == 2) ? (k0g & 1023) : k0g;
            gll16(base + grA0 + ka, lb + ldst0);
            gll16(base + grA1 + ka, lb + ldst1);
        } else if (ten == 3) {
            gll16(Al + grA0 + k0g, lb + ldst0);
            gll16(Al + grA1 + k0g, lb + ldst1);
        } else {
            const u16* b = (ten == 1) ? Bh : Bl;
            gll16(b + grB0 + k0g, lb + ldst0);
            gll16(b + grB1 + k0g, lb + ldst1);
        }
    };

    int offA[8], offB[4];
#pragma unroll
    for (int k = 0; k < 8; ++k) {
        const int r = wr * 128 + k * 16 + fr;
        offA[k] = (r * 4 + (g ^ ((r >> 1) & 3))) * 8;
    }
#pragma unroll
    for (int j = 0; j < 4; ++j) {
        const int r = wc * 64 + j * 16 + fr;
        offB[j] = (r * 4 + (g ^ ((r >> 1) & 3))) * 8;
    }

    short8 fax[4], fay[4], fal[4], fbh[4], fbl[4];

#define PFA_(DST, BUF, TEN, MH)                                                \
    { const u16* pl = &lds[BUF][TEN][0];                                       \
      _Pragma("unroll") for (int i_ = 0; i_ < 4; ++i_)                         \
          DST[i_] = *(const short8*)&pl[offA[(MH) * 4 + i_]]; }
#define PFB_(DST, BUF, TEN)                                                    \
    { const u16* pl = &lds[BUF][TEN][0];                                       \
      _Pragma("unroll") for (int j_ = 0; j_ < 4; ++j_)                         \
          DST[j_] = *(const short8*)&pl[offB[j_]]; }
#define MFMA16(FA, FB, MH)                                                     \
    __builtin_amdgcn_s_setprio(1);                                             \
    _Pragma("unroll") for (int i_ = 0; i_ < 4; ++i_)                           \
        _Pragma("unroll") for (int j_ = 0; j_ < 4; ++j_)                       \
            acc[(MH) * 4 + i_][j_] = __builtin_amdgcn_mfma_f32_16x16x32_bf16(  \
                FA[i_], FB[j_], acc[(MH) * 4 + i_][j_], 0, 0, 0);              \
    __builtin_amdgcn_s_setprio(0);

    // prologue: stage tile 0 (all tensors), retire Ah,Bh; PF ph1 frags
    stage(0, 0); stage(0, 1); stage(0, 2);
    if (NPROD == 3) stage(0, 3);
    if (NPROD == 3) { asm volatile("s_waitcnt vmcnt(4)" ::: "memory"); }
    else            { asm volatile("s_waitcnt vmcnt(2)" ::: "memory"); }
    __builtin_amdgcn_s_barrier();
    PFB_(fbh, 0, 1)
    PFA_(fax, 0, 0, 0)
    __builtin_amdgcn_sched_barrier(0);

    const int NT = NKSEG * 32;
    for (int t = 0; t < NT; ++t) {
        const int cur = t & 1, nxt = cur ^ 1;
        const bool nl = (t + 1 < NT);

        // ph1: Ah·Bh mh0; stage Ah(t+1); wait retires Bl(t); PF fbl
        if (nl) stage(t + 1, 0);
        if (nl) {
            if (NPROD == 3) { asm volatile("s_waitcnt vmcnt(4)" ::: "memory"); }
            else            { asm volatile("s_waitcnt vmcnt(2)" ::: "memory"); }
        } else { asm volatile("s_waitcnt vmcnt(0)" ::: "memory"); }
        __builtin_amdgcn_s_barrier();
        PFB_(fbl, cur, 2)
        __builtin_amdgcn_sched_barrier(0);
        MFMA16(fax, fbh, 0)

        // ph2: Ah·Bl mh0; stage Bh(t+1); [NPROD3: wait retires Al(t), PF fal]
        if (nl) stage(t + 1, 1);
        if (NPROD == 3) {
            if (nl) { asm volatile("s_waitcnt vmcnt(4)" ::: "memory"); }
            else    { asm volatile("s_waitcnt vmcnt(0)" ::: "memory"); }
        }
        __builtin_amdgcn_s_barrier();
        if (NPROD == 3) { PFA_(fal, cur, 3, 0) }
        else            { PFA_(fay, cur, 0, 1) }
        __builtin_amdgcn_sched_barrier(0);
        MFMA16(fax, fbl, 0)

        if (NPROD == 3) {
            // ph3: Al·Bh mh0; stage Bl(t+1); PF fay (Ah mh1)
            if (nl) stage(t + 1, 2);
            __builtin_amdgcn_s_barrier();
            PFA_(fay, cur, 0, 1)
            __builtin_amdgcn_sched_barrier(0);
            MFMA16(fal, fbh, 0)
            // ph4: Ah·Bh mh1; stage Al(t+1); PF fal (Al mh1; old fal dead)
            if (nl) stage(t + 1, 3);
            __builtin_amdgcn_s_barrier();
            PFA_(fal, cur, 3, 1)
            __builtin_amdgcn_sched_barrier(0);
            MFMA16(fay, fbh, 1)
            // ph5: Al·Bh mh1 — LAST use of fbh
            __builtin_amdgcn_s_barrier();
            __builtin_amdgcn_sched_barrier(0);
            MFMA16(fal, fbh, 1)
            // ph6: Ah·Bl mh1 (fay,fbl only); wait retires Ah,Bh(t+1);
            //      PF next fbh,fax — both dead here
            if (nl) { asm volatile("s_waitcnt vmcnt(4)" ::: "memory"); }
            __builtin_amdgcn_s_barrier();
            if (nl) { PFB_(fbh, nxt, 1) PFA_(fax, nxt, 0, 0) }
            __builtin_amdgcn_sched_barrier(0);
            MFMA16(fay, fbl, 1)
        } else {
            // ph3: Ah·Bh mh1; stage Bl(t+1) — LAST use of fbh
            if (nl) stage(t + 1, 2);
            __builtin_amdgcn_s_barrier();
            __builtin_amdgcn_sched_barrier(0);
            MFMA16(fay, fbh, 1)
            // ph4: Ah·Bl mh1 (fay,fbl only); wait retires Ah,Bh(t+1);
            //      PF next fbh,fax — both dead here
            if (nl) { asm volatile("s_waitcnt vmcnt(2)" ::: "memory"); }
            __builtin_amdgcn_s_barrier();
            if (nl) { PFB_(fbh, nxt, 1) PFA_(fax, nxt, 0, 0) }
            __builtin_amdgcn_sched_barrier(0);
            MFMA16(fay, fbl, 1)
        }
    }
#undef PFA_
#undef PFB_
#undef MFMA16

    // epilogue: LDS-transposed coalesced stores
    __syncthreads();
    u16* ebase = (u16*)&lds[0][0][0];
    const int lrow = wr * 16 + g * 4;
#pragma unroll
    for (int mi = 0; mi < 8; ++mi) {
        if (EPI == E_F32 || EPI == E_TANH) {
            float* el = (float*)ebase;               // [32][260]
#pragma unroll
            for (int nj = 0; nj < 4; ++nj) {
                const int col = wc * 64 + nj * 16 + fr;
                const float bv = (EPI == E_TANH) ? bias[bn + col] : 0.0f;
#pragma unroll
                for (int r = 0; r < 4; ++r) {
                    float vv = acc[mi][nj][r];
                    if (EPI == E_TANH) {
                        const float e = __expf(2.0f * (vv + bv));
                        vv = 1.0f - 2.0f / (e + 1.0f);
                    }
                    el[(lrow + r) * 260 + col] = vv;
                }
            }
            __syncthreads();
#pragma unroll
            for (int q = 0; q < 4; ++q) {
                const int c = tid + 512 * q;
                const int r32 = c >> 6, c4 = (c & 63) * 4;
                f32x4 vv = *(const f32x4*)&el[r32 * 260 + c4];
                const int grow = bm + (r32 >> 4) * 128 + mi * 16 + (r32 & 15);
                *(f32x4*)&Cf[(long)grow * ldC + bn + c4] = vv;
            }
        } else if (EPI == E_SPLIT) {
            u32* el = (u32*)ebase;                   // [32][260] packed h|l
#pragma unroll
            for (int nj = 0; nj < 4; ++nj) {
                const int col = wc * 64 + nj * 16 + fr;
#pragma unroll
                for (int r = 0; r < 4; ++r) {
                    const float vv = acc[mi][nj][r];
                    const u16 h = f2h(vv);
                    const u16 lo = f2h(vv - h2f(h));
                    el[(lrow + r) * 260 + col] = (u32)h | ((u32)lo << 16);
                }
            }
            __syncthreads();
#pragma unroll
            for (int q = 0; q < 4; ++q) {
                const int c = tid + 512 * q;
                const int r32 = c >> 6, c4 = (c & 63) * 4;
                const u32* p = &el[r32 * 260 + c4];
                u16x4 hh, ll;
#pragma unroll
                for (int e = 0; e < 4; ++e) {
                    const u32 pv = p[e];
                    hh[e] = (u16)(pv & 0xffffu);
                    ll[e] = (u16)(pv >> 16);
                }
                const int grow = bm + (r32 >> 4) * 128 + mi * 16 + (r32 & 15);
                const long o = (long)grow * ldC + bn + c4;
                *(u16x4*)&Ch[o] = hh;
                *(u16x4*)&Cl[o] = ll;
            }
        } else {   // E_H
            u16* el = ebase;                         // [32][264]
#pragma unroll
            for (int nj = 0; nj < 4; ++nj) {
                const int col = wc * 64 + nj * 16 + fr;
#pragma unroll
                for (int r = 0; r < 4; ++r)
                    el[(lrow + r) * 264 + col] = f2h(acc[mi][nj][r]);
            }
            __syncthreads();
#pragma unroll
            for (int q = 0; q < 2; ++q) {
                const int c = tid + 512 * q;
                const int r32 = c >> 5, c8 = (c & 31) * 8;
                short8 vv = *(const short8*)&el[r32 * 264 + c8];
                const int grow = bm + (r32 >> 4) * 128 + mi * 16 + (r32 & 15);
                *(short8*)&Ch[(long)grow * ldC + bn + c8] = vv;
            }
        }
        __syncthreads();
    }
}

// ---------------------------------------------------------------------------
// R9-family 256x256 GEMM over K'-extension — retained for K3 (NSEG=1).
// ---------------------------------------------------------------------------
template<int NSEG, int EPI>
__global__ __launch_bounds__(512, 2) void gemm8(
    Segs sg, int ldA, int ldB, int zshift,
    long sA, long sB, long sC,
    const float* __restrict__ bias,
    float* __restrict__ Cf, u16* __restrict__ Ch, u16* __restrict__ Cl,
    int ldC)
{
    __shared__ u16 lds[2][2][2][256 * 32];

    const int tid = threadIdx.x;
    const int l = tid & 63, w = tid >> 6;
    const int wr = w >> 2, wc = w & 3;
    const int fr = l & 15, g = l >> 4;

    const int id = blockIdx.x;
    const int v = ((id & 7) << 5) | (id >> 3);
    const int z = v >> zshift;
    const int rest = v & ((1 << zshift) - 1);
    const int bm = (rest >> 2) * 256;
    const int bn = (rest & 3) * 256;

    const u16* Aseg[4]; const u16* Bseg[4];
#pragma unroll
    for (int s = 0; s < NSEG; ++s) {
        Aseg[s] = sg.a[s] + (long)z * sA;
        Bseg[s] = sg.b[s] + (long)z * sB;
    }
    if (EPI == E_F32 || EPI == E_TANH) Cf += (long)z * sC;
    else { Ch += (long)z * sC; if (EPI == E_SPLIT) Cl += (long)z * sC; }

    f32x4 acc[8][4] = {};

    const int srow = tid >> 2, sch = tid & 3;
    const int skc = sch ^ ((srow >> 1) & 3);
    const long grA0 = (long)(bm + srow) * ldA + skc * 8;
    const long grA1 = (long)(bm + 128 + srow) * ldA + skc * 8;
    const long grB0 = (long)(bn + srow) * ldB + skc * 8;
    const long grB1 = (long)(bn + 128 + srow) * ldB + skc * 8;
    const int ldst0 = (tid & ~63) * 8;
    const int ldst1 = (512 + (tid & ~63)) * 8;

    auto stage = [&](int tile, int kh, int tensor) {
        const int k0g = tile * 64 + kh * 32;
        const int seg = k0g >> 10, kl = k0g & 1023;
        u16* lb = &lds[tile & 1][tensor][kh][0];
        if (tensor) {
            const u16* b = Bseg[seg];
            gll16(b + grB0 + kl, lb + ldst0);
            gll16(b + grB1 + kl, lb + ldst1);
        } else {
            const u16* a = Aseg[seg];
            gll16(a + grA0 + kl, lb + ldst0);
            gll16(a + grA1 + kl, lb + ldst1);
        }
    };

    int offA[8], offB[4];
#pragma unroll
    for (int k = 0; k < 8; ++k) {
        const int r = wr * 128 + k * 16 + fr;
        offA[k] = (r * 4 + (g ^ ((r >> 1) & 3))) * 8;
    }
#pragma unroll
    for (int j = 0; j < 4; ++j) {
        const int r = wc * 64 + j * 16 + fr;
        offB[j] = (r * 4 + (g ^ ((r >> 1) & 3))) * 8;
    }

    short8 faX[4], faY[4], fbA[4], fbB[4];

#define PFA(FA, BUF, KS, MH)                                                   \
    { const u16* pl = &lds[BUF][0][KS][0];                                     \
      _Pragma("unroll") for (int i_ = 0; i_ < 4; ++i_)                         \
          FA[i_] = *(const short8*)&pl[offA[(MH) * 4 + i_]]; }
#define PFB(FB, BUF, KS)                                                       \
    { const u16* pl = &lds[BUF][1][KS][0];                                     \
      _Pragma("unroll") for (int j_ = 0; j_ < 4; ++j_)                         \
          FB[j_] = *(const short8*)&pl[offB[j_]]; }
#define MFMA16(FA, FB, MH)                                                     \
    __builtin_amdgcn_s_setprio(1);                                             \
    _Pragma("unroll") for (int i_ = 0; i_ < 4; ++i_)                           \
        _Pragma("unroll") for (int j_ = 0; j_ < 4; ++j_)                       \
            acc[(MH) * 4 + i_][j_] = __builtin_amdgcn_mfma_f32_16x16x32_bf16(  \
                FA[i_], FB[j_], acc[(MH) * 4 + i_][j_], 0, 0, 0);              \
    __builtin_amdgcn_s_setprio(0);

    stage(0, 0, 0); stage(0, 0, 1); stage(0, 1, 0); stage(0, 1, 1);
    asm volatile("s_waitcnt vmcnt(0)" ::: "memory");
    __builtin_amdgcn_s_barrier();
    PFB(fbA, 0, 0)
    PFA(faX, 0, 0, 0)
    __builtin_amdgcn_sched_barrier(0);

    const int NT = NSEG * 16;
    for (int t = 0; t < NT; ++t) {
        const int cur = t & 1, nxt = cur ^ 1;
        const bool nl = (t + 1 < NT);

        if (nl) stage(t + 1, 0, 0);
        __builtin_amdgcn_s_barrier();
        PFA(faY, cur, 0, 1)
        __builtin_amdgcn_sched_barrier(0);
        MFMA16(faX, fbA, 0)

        if (nl) stage(t + 1, 0, 1);
        if (nl) { asm volatile("s_waitcnt vmcnt(4)" ::: "memory"); }
        else    { asm volatile("s_waitcnt vmcnt(0)" ::: "memory"); }
        __builtin_amdgcn_s_barrier();
        PFB(fbB, cur, 1)
        PFA(faX, cur, 1, 0)
        __builtin_amdgcn_sched_barrier(0);
        MFMA16(faY, fbA, 1)

        if (nl) stage(t + 1, 1, 0);
        __builtin_amdgcn_s_barrier();
        PFA(faY, cur, 1, 1)
        __builtin_amdgcn_sched_barrier(0);
        MFMA16(faX, fbB, 0)

        if (nl) stage(t + 1, 1, 1);
        if (nl) { asm volatile("s_waitcnt vmcnt(4)" ::: "memory"); }
        __builtin_amdgcn_s_barrier();
        PFB(fbA, nxt, 0)
        PFA(faX, nxt, 0, 0)
        __builtin_amdgcn_sched_barrier(0);
        MFMA16(faY, fbB, 1)
    }
#undef PFA
#undef PFB
#undef MFMA16

    __syncthreads();
    const int lrow = wr * 16 + g * 4;
#pragma unroll
    for (int mi = 0; mi < 8; ++mi) {
        u16* el16 = (u16*)&lds[0][0][0][0];
        if (EPI == E_H) {
#pragma unroll
            for (int nj = 0; nj < 4; ++nj) {
                const int col = wc * 64 + nj * 16 + fr;
#pragma unroll
                for (int r = 0; r < 4; ++r)
                    el16[(lrow + r) * 264 + col] = f2h(acc[mi][nj][r]);
            }
            __syncthreads();
#pragma unroll
            for (int q = 0; q < 2; ++q) {
                const int c = tid + 512 * q;
                const int r32 = c >> 5, c8 = (c & 31) * 8;
                short8 vv = *(const short8*)&el16[r32 * 264 + c8];
                const int grow = bm + (r32 >> 4) * 128 + mi * 16 + (r32 & 15);
                *(short8*)&Ch[(long)grow * ldC + bn + c8] = vv;
            }
        } else {
            float* el = (float*)&lds[0][0][0][0];
#pragma unroll
            for (int nj = 0; nj < 4; ++nj) {
                const int col = wc * 64 + nj * 16 + fr;
                const float bv = (EPI == E_TANH) ? bias[bn + col] : 0.0f;
#pragma unroll
                for (int r = 0; r < 4; ++r) {
                    float vv = acc[mi][nj][r];
                    if (EPI == E_TANH) {
                        const float e = __expf(2.0f * (vv + bv));
                        vv = 1.0f - 2.0f / (e + 1.0f);
                    }
                    el[(lrow + r) * 260 + col] = vv;
                }
            }
            __syncthreads();
#pragma unroll
            for (int q = 0; q < 4; ++q) {
                const int c = tid + 512 * q;
                const int r32 = c >> 6, c4 = (c & 63) * 4;
                f32x4 vv = *(const f32x4*)&el[r32 * 260 + c4];
                const int grow = bm + (r32 >> 4) * 128 + mi * 16 + (r32 & 15);
                *(f32x4*)&Cf[(long)grow * ldC + bn + c4] = vv;
            }
        }
        __syncthreads();
    }
}

// ---------------------------------------------------------------------------
__global__ __launch_bounds__(256) void split_f32(
    const float* __restrict__ in, u16* __restrict__ hi, u16* __restrict__ lo,
    long n4)
{
    long i = (long)blockIdx.x * blockDim.x + threadIdx.x;
    const long stride = (long)gridDim.x * blockDim.x;
    for (; i < n4; i += stride) {
        f32x4 v = *(const f32x4*)(in + i * 4);
        u16x4 h4, l4;
#pragma unroll
        for (int e = 0; e < 4; ++e) {
            u16 h_ = f2h(v[e]);
            h4[e] = h_; l4[e] = f2h(v[e] - h2f(h_));
        }
        *(u16x4*)(hi + i * 4) = h4;
        *(u16x4*)(lo + i * 4) = l4;
    }
}

__global__ __launch_bounds__(256) void split3(
    const float* __restrict__ q,  u16* __restrict__ qh,  u16* __restrict__ ql,
    const float* __restrict__ wi, u16* __restrict__ wih, u16* __restrict__ wil,
    const float* __restrict__ wo, u16* __restrict__ woh, u16* __restrict__ wol,
    long nq4, long nwi4, long nwo4)
{
    const long total = nq4 + nwi4 + nwo4;
    long i = (long)blockIdx.x * blockDim.x + threadIdx.x;
    const long stride = (long)gridDim.x * blockDim.x;
    for (; i < total; i += stride) {
        const float* src; u16 *hi, *lo; long off;
        if (i < nq4)              { src = q;  hi = qh;  lo = ql;  off = i; }
        else if (i < nq4 + nwi4)  { src = wi; hi = wih; lo = wil; off = i - nq4; }
        else                      { src = wo; hi = woh; lo = wol; off = i - nq4 - nwi4; }
        f32x4 v = *(const f32x4*)(src + off * 4);
        u16x4 h4, l4;
#pragma unroll
        for (int e = 0; e < 4; ++e) {
            u16 h_ = f2h(v[e]);
            h4[e] = h_; l4[e] = f2h(v[e] - h2f(h_));
        }
        *(u16x4*)(hi + off * 4) = h4;
        *(u16x4*)(lo + off * 4) = l4;
    }
}

__global__ __launch_bounds__(256) void split_enc_fused(
    const float* __restrict__ in, u16* __restrict__ hi, u16* __restrict__ lo,
    u16* __restrict__ outT)
{
    __shared__ u16 t[64][72];
    const int z = blockIdx.z, sb = blockIdx.x * 64, hb = blockIdx.y * 64;
    const int c4 = (threadIdx.x & 15) * 4, r0 = threadIdx.x >> 4;
    const float* src = in + ((long)z * SS + sb) * HH + hb;
    u16* dhi = hi + ((long)z * SS + sb) * HH + hb;
    u16* dlo = lo + ((long)z * SS + sb) * HH + hb;
#pragma unroll
    for (int i = 0; i < 4; ++i) {
        const int r = r0 + i * 16;
        f32x4 v = *(const f32x4*)(src + (long)r * HH + c4);
        u16x4 h4, l4;
#pragma unroll
        for (int j = 0; j < 4; ++j) {
            u16 h_ = f2h(v[j]);
            h4[j] = h_; l4[j] = f2h(v[j] - h2f(h_));
        }
        *(u16x4*)(dhi + (long)r * HH + c4) = h4;
        *(u16x4*)(dlo + (long)r * HH + c4) = l4;
        t[c4 + 0][r] = h4[0]; t[c4 + 1][r] = h4[1];
        t[c4 + 2][r] = h4[2]; t[c4 + 3][r] = h4[3];
    }
    __syncthreads();
    u16* dst = outT + ((long)z * HH + hb) * SS + sb;
#pragma unroll
    for (int i = 0; i < 4; ++i) {
        const int r = r0 + i * 16;
        u16x4 o;
#pragma unroll
        for (int j = 0; j < 4; ++j) o[j] = t[r][c4 + j];
        *(u16x4*)(dst + (long)r * SS + c4) = o;
    }
}

__global__ __launch_bounds__(256) void transpose_h(
    const u16* __restrict__ in, u16* __restrict__ out)
{
    __shared__ u16 t[64][72];
    const int z = blockIdx.z, sb = blockIdx.x * 64, hb = blockIdx.y * 64;
    const int c4 = (threadIdx.x & 15) * 4, r0 = threadIdx.x >> 4;
    const u16* src = in + ((long)z * SS + sb) * HH + hb;
#pragma unroll
    for (int i = 0; i < 4; ++i) {
        const int r = r0 + i * 16;
        u16x4 v = *(const u16x4*)(src + (long)r * HH + c4);
        t[c4 + 0][r] = v[0]; t[c4 + 1][r] = v[1];
        t[c4 + 2][r] = v[2]; t[c4 + 3][r] = v[3];
    }
    __syncthreads();
    u16* dst = out + ((long)z * HH + hb) * SS + sb;
#pragma unroll
    for (int i = 0; i < 4; ++i) {
        const int r = r0 + i * 16;
        u16x4 o;
#pragma unroll
        for (int j = 0; j < 4; ++j) o[j] = t[r][c4 + j];
        *(u16x4*)(dst + (long)r * SS + c4) = o;
    }
}

__global__ __launch_bounds__(256) void softmax_mask(
    const float* __restrict__ Sc, u16* __restrict__ Ph,
    const int* __restrict__ lens)
{
    const int row = blockIdx.x;
    const int b = row >> 9;
    const int len = lens[b];
    const float* p = Sc + (long)row * SS;

    const int tid = threadIdx.x;
    const int s0 = tid * 4;
    f32x4 v = *(const f32x4*)(p + s0);
    float vals[4] = {v.x, v.y, v.z, v.w};

    float mx = -INFINITY;
#pragma unroll
    for (int j = 0; j < 4; ++j) {
        if (s0 + j >= len) vals[j] = -INFINITY;
        mx = fmaxf(mx, vals[j]);
    }
    for (int off = 32; off; off >>= 1) mx = fmaxf(mx, __shfl_xor(mx, off, 64));

    __shared__ float redm[4];
    __shared__ float reds[4];
    const int wave = tid >> 6, lane = tid & 63;
    if (lane == 0) redm[wave] = mx;
    __syncthreads();
    mx = fmaxf(fmaxf(redm[0], redm[1]), fmaxf(redm[2], redm[3]));

    float sum = 0.0f;
#pragma unroll
    for (int j = 0; j < 4; ++j) {
        vals[j] = __expf(vals[j] - mx);
        sum += vals[j];
    }
    for (int off = 32; off; off >>= 1) sum += __shfl_xor(sum, off, 64);
    if (lane == 0) reds[wave] = sum;
    __syncthreads();
    sum = reds[0] + reds[1] + reds[2] + reds[3];

    const float inv = 1.0f / sum;
    u16x4 o;
#pragma unroll
    for (int j = 0; j < 4; ++j) o[j] = f2h(vals[j] * inv);
    *(u16x4*)(Ph + (long)row * SS + s0) = o;
}

// ---------------------------------------------------------------------------
extern "C" void kernel_launch(void* const* d_in, const int* in_sizes, int n_in,
                              void* d_out, int out_size, void* d_ws, size_t ws_size,
                              hipStream_t stream)
{
    const float* query = (const float*)d_in[0];
    const float* enc   = (const float*)d_in[1];
    const int*   lens  = (const int*)d_in[2];
    const float* W_in  = (const float*)d_in[3];
    const float* W_out = (const float*)d_in[4];
    const float* b_out = (const float*)d_in[5];
    float* out = (float*)d_out;

    const long MQ = (long)BB * TT;

    u16* qh   = (u16*)d_ws;
    u16* ql   = qh   + MQ * HH;
    u16* qwh  = ql   + MQ * HH;
    u16* qwl  = qwh  + MQ * HH;
    u16* ench = qwl  + MQ * HH;
    u16* encl = ench + (long)BB * SS * HH;
    u16* ph   = encl + (long)BB * SS * HH;
    u16* wih  = ph   + MQ * SS;
    u16* wil  = wih  + (long)HH * HH;
    u16* woh  = wil  + (long)HH * HH;
    u16* wol  = woh  + (long)HH * 2 * HH;
    float* scores = (float*)(wol + (long)HH * 2 * HH);
    u16* ch   = ql;                               // overlays ql (dead after K1)

    u16* encT_ded = (u16*)(scores + MQ * SS);
    const size_t need_fused =
        (size_t)((u16*)(scores + MQ * SS) - (u16*)d_ws) * 2 + (size_t)BB * HH * SS * 2;
    const bool fused = (ws_size >= need_fused);
    u16* encTh = fused ? encT_ded : (u16*)scores;

    split3<<<2048, 256, 0, stream>>>(
        query, qh, ql, W_in, wih, wil, W_out, woh, wol,
        MQ * HH / 4, (long)HH * HH / 4, (long)HH * 2 * HH / 4);
    if (fused) {
        split_enc_fused<<<dim3(16, 16, 32), 256, 0, stream>>>(
            enc, ench, encl, encTh);
    } else {
        split_f32<<<2048, 256, 0, stream>>>(enc, ench, encl,
                                            (long)BB * SS * HH / 4);
    }

    // K1: qw = query @ W_in^T  (native 3-product, K=1024)
    gemm_np<3, 1, E_SPLIT><<<256, 512, 0, stream>>>(
        qh, nullptr, ql, wih, wil, HH, HH, 8, 0L, 0L, 0L,
        nullptr, nullptr, qwh, qwl, HH);

    // K2: scores[b] = qw[b] @ enc[b]^T  (native 3-product), 32 batches
    gemm_np<3, 1, E_F32><<<256, 512, 0, stream>>>(
        qwh, nullptr, qwl, ench, encl, HH, HH, 3,
        (long)TT * HH, (long)SS * HH, (long)TT * SS,
        nullptr, scores, nullptr, nullptr, SS);

    softmax_mask<<<BB * TT, 256, 0, stream>>>(scores, ph, lens);

    if (!fused) {
        transpose_h<<<dim3(16, 16, 32), 256, 0, stream>>>(ench, encTh);
    }

    // K3: c[b] = P[b] @ enc[b]  (1-product; gemm8 NSEG=1 is native)
    Segs s3 = {{ph, nullptr, nullptr, nullptr}, {encTh, nullptr, nullptr, nullptr}};
    gemm8<1, E_H><<<256, 512, 0, stream>>>(
        s3, SS, SS, 3, (long)TT * SS, (long)HH * SS, (long)TT * HH,
        nullptr, nullptr, ch, nullptr, HH);

    // K4: out = tanh([qh|ch] @ [woh + wol]^T + b)  (native 2-product, K=2048)
    gemm_np<2, 2, E_TANH><<<256, 512, 0, stream>>>(
        qh, ch, nullptr, woh, wol, HH, 2 * HH, 8, 0L, 0L, 0L,
        b_out, out, nullptr, nullptr, HH);
}